// Round 22
// baseline (825.117 us; speedup 1.0000x reference)
//
#include <hip/hip_runtime.h>

#define HID 51
#define TLEN 1024
#define NBATCH 4
#define NW 7
#define NTH (NW * 64)    // 448 threads; each wave owns tiles {w, w+7}

typedef _Float16 f16x8 __attribute__((ext_vector_type(8)));
typedef float    f32x4 __attribute__((ext_vector_type(4)));

#define LOG2E 1.4426950408889634f

__device__ __forceinline__ float frcp(float v){ return __builtin_amdgcn_rcpf(v); }
// input already scaled by log2e (or 2*log2e for tanh-gate)
__device__ __forceinline__ float sigm2(float v){ return frcp(1.f + __builtin_amdgcn_exp2f(-v)); }
__device__ __forceinline__ float tanh_c(float c){   // c in true domain
    return fmaf(2.f, frcp(1.f + __builtin_amdgcn_exp2f(-2.f*LOG2E*c)), -1.f);
}

// Fragment layout (validated R4): lane l reads 16B at half-index kb*512 + l*8
// covering k = 32*kb + 8*(l>>4) + 0..7, col = l&15.
// Writer (unit j, col n): half-index = (j>>5)<<9 + (n + ((j>>3)&3)*16)*8 + (j&7).
// Balanced 2-phase pipeline (R17/R20) + BALANCED EPILOGUE: chain c -> wave c%7,
// lane c/7, so every wave runs ~29-30 chains in BOTH phases (was: contiguous tid
// ranges -> 3-4 straggler waves per phase -> barrier waits one epi duration 2x/step).
// Each lane handles the same (unit,batch) for L0 (cst0, phase B) and L1 (cst1,
// phase A); bias/x folded into GEMM C-init so epilogue is pure gates.
//   Phase A(s): GEMM L0(s)  ||  EPI-L1 on PRE1(s-2) -> h1(s-2)
//   Phase B(s): GEMM L1(s-1) ||  EPI-L0 on PRE0(s)  -> h0(s)
// Projection: M-row 204 (tile 12) carries W_lin over the h1 K-range; output
// staged in LDS OUT, flushed after the loop.

__global__ __launch_bounds__(NTH)
void lstm2_mfma(const float* __restrict__ x,
                const float* __restrict__ W_ih0, const float* __restrict__ W_hh0,
                const float* __restrict__ b_ih0, const float* __restrict__ b_hh0,
                const float* __restrict__ W_ih1, const float* __restrict__ W_hh1,
                const float* __restrict__ b_ih1, const float* __restrict__ b_hh1,
                const float* __restrict__ W_lin, const float* __restrict__ b_lin,
                float* __restrict__ out)
{
    const int tid = threadIdx.x;
    const int w = tid >> 6;          // wave 0..6; tiles {w, w+7}
    const int l = tid & 63;
    const int n = l & 15;            // column slot (0-3 real batch)
    const int p = l >> 4;            // lane group 0..3

    __shared__ _Float16 H0[2][1024];
    __shared__ _Float16 H1[2][1024];
    __shared__ __align__(16) float PRE0[HID*NBATCH*4];    // 204 x f32x4
    __shared__ __align__(16) float PRE1[HID*NBATCH*4];    // 204 x f32x4
    __shared__ float XS[NBATCH][1032];                    // staged x, padded rows
    __shared__ float OUT[NBATCH][TLEN];                   // staged outputs

    for (int i = tid; i < 1024; i += NTH){
        H0[0][i] = (_Float16)0.f; H0[1][i] = (_Float16)0.f;
        H1[0][i] = (_Float16)0.f; H1[1][i] = (_Float16)0.f;
    }
    const long long bb = (long long)blockIdx.x * NBATCH;
    for (int i = tid; i < NBATCH*TLEN; i += NTH){
        const int r = i >> 10, c = i & 1023;
        XS[r][c] = x[(bb + r)*TLEN + c];
    }

    // ---- GEMM-role: persistent fp16 weight fragments + C-init consts ----
    f16x8 A0[2][2];   // W_hh0, K=64
    f16x8 A1[2][4];   // [0..1]=W_ih1 (k<64), [2..3]=W_hh1 (k64..127) + proj row 204
    f32x4 b0c[2], wx0c[2], b1c[2];
    int  jet[2]; bool stAt[2];
    #pragma unroll
    for (int t=0; t<2; ++t){
        const int tile = w + 7*t;             // 0..13 (13 = zero dummy)
        const int ar = 16*tile + n;           // A-row = gate g = 4j + r
        const int aj = ar >> 2, arr = ar & 3;
        const bool rowv = (aj < HID);
        const int orow = arr*HID + aj;
        const float gsc = (arr == 2) ? 2.f*LOG2E : LOG2E;
        #pragma unroll
        for (int kb=0; kb<2; ++kb){
            f16x8 hi;
            #pragma unroll
            for (int jj=0; jj<8; ++jj){
                const int k = kb*32 + 8*p + jj;
                const float wv = (rowv && k < HID) ? gsc * W_hh0[orow*HID + k] : 0.f;
                hi[jj] = (_Float16)wv;
            }
            A0[t][kb] = hi;
        }
        #pragma unroll
        for (int kb=0; kb<4; ++kb){
            f16x8 hi;
            #pragma unroll
            for (int jj=0; jj<8; ++jj){
                const int k = kb*32 + 8*p + jj;   // 0..127: [h0 ; h1]
                float wv = 0.f;
                if (rowv){
                    if (k < 64) { if (k < HID) wv = gsc * W_ih1[orow*HID + k]; }
                    else        { const int kk = k - 64; if (kk < HID) wv = gsc * W_hh1[orow*HID + kk]; }
                } else if (ar == 204 && k >= 64){ // projection row (unscaled!)
                    const int kk = k - 64; if (kk < HID) wv = W_lin[kk];
                }
                hi[jj] = (_Float16)wv;
            }
            A1[t][kb] = hi;
        }
        jet[t]  = 4*tile + p;
        stAt[t] = (n < NBATCH) && (jet[t] < HID);
        const bool jev = (jet[t] < HID) && (tile < 13);
        #pragma unroll
        for (int r4=0; r4<4; ++r4){
            const float gs4 = (r4 == 2) ? 2.f*LOG2E : LOG2E;
            const int oe = r4*HID + jet[t];
            b0c[t][r4]  = jev ? gs4 * (b_ih0[oe] + b_hh0[oe]) : 0.f;
            wx0c[t][r4] = jev ? gs4 * W_ih0[oe] : 0.f;
            b1c[t][r4]  = jev ? gs4 * (b_ih1[oe] + b_hh1[oe]) : 0.f;
        }
    }
    const bool outm = (w == 5) && (p == 3) && (n < NBATCH);   // tile 12, row 204
    const float blin = b_lin[0];

    // ---- epilogue-role: balanced chain assignment, one chain id per lane ----
    // chain c = 7*l + w  (c < 204)  -> every wave gets 29-30 active lanes.
    const int cch = 7*l + w;
    const bool eact = (cch < HID*NBATCH);
    const int jq = cch >> 2, nq = cch & 3;
    const int widxq = ((jq>>5)<<9) + (nq + ((jq>>3)&3)*16)*8 + (jq&7);
    float cst0 = 0.f, cst1 = 0.f;   // L0 and L1 cell states of chain cch

    __syncthreads();

    for (int s = 0; s <= TLEN + 1; ++s){
        const int pw = s & 1, prv = pw ^ 1;

        // ================= PHASE A =================
        // rb = h0(s-1) fragments — used by L0 now AND L1 in phase B (reg-carried)
        f16x8 rb[2];
        #pragma unroll
        for (int kb=0; kb<2; ++kb)
            rb[kb] = *reinterpret_cast<const f16x8*>(&H0[prv][kb*512 + l*8]);

        if (s < TLEN){
            const float xv = XS[n & 3][s];
            f32x4 a0 = b0c[0], a1 = b0c[1];
            #pragma unroll
            for (int r4=0; r4<4; ++r4){
                a0[r4] = fmaf(xv, wx0c[0][r4], a0[r4]);
                a1[r4] = fmaf(xv, wx0c[1][r4], a1[r4]);
            }
            __builtin_amdgcn_s_setprio(1);
            a0 = __builtin_amdgcn_mfma_f32_16x16x32_f16(A0[0][0], rb[0], a0, 0,0,0);
            a1 = __builtin_amdgcn_mfma_f32_16x16x32_f16(A0[1][0], rb[0], a1, 0,0,0);
            a0 = __builtin_amdgcn_mfma_f32_16x16x32_f16(A0[0][1], rb[1], a0, 0,0,0);
            a1 = __builtin_amdgcn_mfma_f32_16x16x32_f16(A0[1][1], rb[1], a1, 0,0,0);
            __builtin_amdgcn_s_setprio(0);
            if (stAt[0]) *reinterpret_cast<f32x4*>(&PRE0[(jet[0]*NBATCH + n)*4]) = a0;
            if (stAt[1]) *reinterpret_cast<f32x4*>(&PRE0[(jet[1]*NBATCH + n)*4]) = a1;
        }
        // EPI-L1: gates of L1(s-2) from PRE1 -> h1(s-2) into H1[s&1]
        if (eact && s >= 2 && s <= TLEN + 1){
            const f32x4 pre = *reinterpret_cast<const f32x4*>(&PRE1[cch*4]);
            const float gi = sigm2(pre[0]);
            const float gf = sigm2(pre[1]);
            const float gg = fmaf(2.f, sigm2(pre[2]), -1.f);
            const float go = sigm2(pre[3]);
            cst1 = fmaf(gf, cst1, gi*gg);
            H1[pw][widxq] = (_Float16)(go * tanh_c(cst1));
        }
        __syncthreads();   // #1: PRE0(s), h1(s-2) visible

        // ================= PHASE B =================
        if (s >= 1){
            // r1 = h1(s-2) fragments (just published)
            f16x8 r1[2];
            #pragma unroll
            for (int kb=0; kb<2; ++kb)
                r1[kb] = *reinterpret_cast<const f16x8*>(&H1[pw][kb*512 + l*8]);
            __builtin_amdgcn_s_setprio(1);
            f32x4 b0 = b1c[0], b1 = {0.f,0.f,0.f,0.f};
            f32x4 c0 = b1c[1], c1 = {0.f,0.f,0.f,0.f};
            b0 = __builtin_amdgcn_mfma_f32_16x16x32_f16(A1[0][0], rb[0], b0, 0,0,0);
            c0 = __builtin_amdgcn_mfma_f32_16x16x32_f16(A1[1][0], rb[0], c0, 0,0,0);
            b1 = __builtin_amdgcn_mfma_f32_16x16x32_f16(A1[0][2], r1[0], b1, 0,0,0);
            c1 = __builtin_amdgcn_mfma_f32_16x16x32_f16(A1[1][2], r1[0], c1, 0,0,0);
            b0 = __builtin_amdgcn_mfma_f32_16x16x32_f16(A1[0][1], rb[1], b0, 0,0,0);
            c0 = __builtin_amdgcn_mfma_f32_16x16x32_f16(A1[1][1], rb[1], c0, 0,0,0);
            b1 = __builtin_amdgcn_mfma_f32_16x16x32_f16(A1[0][3], r1[1], b1, 0,0,0);
            c1 = __builtin_amdgcn_mfma_f32_16x16x32_f16(A1[1][3], r1[1], c1, 0,0,0);
            __builtin_amdgcn_s_setprio(0);
            const f32x4 preT0 = b0 + b1;
            const f32x4 preT1 = c0 + c1;
            if (s <= TLEN){
                if (stAt[0]) *reinterpret_cast<f32x4*>(&PRE1[(jet[0]*NBATCH + n)*4]) = preT0;
                if (stAt[1]) *reinterpret_cast<f32x4*>(&PRE1[(jet[1]*NBATCH + n)*4]) = preT1;
            }
            if (outm && s >= 2)
                OUT[n][s-2] = preT1[0] + blin;   // LDS-staged output
        }
        // EPI-L0: gates of L0(s) from PRE0 -> h0(s) into H0[s&1]
        if (eact && s < TLEN){
            const f32x4 pre = *reinterpret_cast<const f32x4*>(&PRE0[cch*4]);
            const float gi = sigm2(pre[0]);
            const float gf = sigm2(pre[1]);
            const float gg = fmaf(2.f, sigm2(pre[2]), -1.f);
            const float go = sigm2(pre[3]);
            cst0 = fmaf(gf, cst0, gi*gg);
            H0[pw][widxq] = (_Float16)(go * tanh_c(cst0));
        }
        __syncthreads();   // #2: PRE1(s-1), h0(s) visible
    }

    // cooperative coalesced flush of staged outputs
    for (int i = tid; i < NBATCH*TLEN; i += NTH){
        const int r = i >> 10, c = i & 1023;
        out[(bb + r)*TLEN + c] = OUT[r][c];
    }
}

extern "C" void kernel_launch(void* const* d_in, const int* in_sizes, int n_in,
                              void* d_out, int out_size, void* d_ws, size_t ws_size,
                              hipStream_t stream) {
    const float* x     = (const float*)d_in[0];
    const float* W_ih0 = (const float*)d_in[1];
    const float* W_hh0 = (const float*)d_in[2];
    const float* b_ih0 = (const float*)d_in[3];
    const float* b_hh0 = (const float*)d_in[4];
    const float* W_ih1 = (const float*)d_in[5];
    const float* W_hh1 = (const float*)d_in[6];
    const float* b_ih1 = (const float*)d_in[7];
    const float* b_hh1 = (const float*)d_in[8];
    const float* W_lin = (const float*)d_in[9];
    const float* b_lin = (const float*)d_in[10];
    float* out = (float*)d_out;

    const int B = in_sizes[0] / TLEN;
    lstm2_mfma<<<dim3(B / NBATCH), dim3(NTH), 0, stream>>>(
        x, W_ih0, W_hh0, b_ih0, b_hh0, W_ih1, W_hh1, b_ih1, b_hh1, W_lin, b_lin, out);
}

// Round 23
// 723.030 us; speedup vs baseline: 1.1412x; 1.1412x over previous
//
#include <hip/hip_runtime.h>

#define HID 51
#define TLEN 1024
#define NBATCH 4
#define NW 7
#define NTH (NW * 64)    // 448 threads; each wave owns tiles {w, w+7}

typedef _Float16 f16x8 __attribute__((ext_vector_type(8)));
typedef float    f32x4 __attribute__((ext_vector_type(4)));

#define LOG2E 1.4426950408889634f

__device__ __forceinline__ float frcp(float v){ return __builtin_amdgcn_rcpf(v); }
// input already scaled by log2e (or 2*log2e for tanh-gate)
__device__ __forceinline__ float sigm2(float v){ return frcp(1.f + __builtin_amdgcn_exp2f(-v)); }
__device__ __forceinline__ float tanh_c(float c){   // c in true domain
    return fmaf(2.f, frcp(1.f + __builtin_amdgcn_exp2f(-2.f*LOG2E*c)), -1.f);
}

// Fragment layout (validated R4): lane l reads 16B at half-index kb*512 + l*8
// covering k = 32*kb + 8*(l>>4) + 0..7, col = l&15.
// Writer (unit j, col n): half-index = (j>>5)<<9 + (n + ((j>>3)&3)*16)*8 + (j&7).
// Balanced 2-phase pipeline (R17/R20 — session best, 723 us):
//   Phase A(s): GEMM L0(s)  ||  EPI-L1 on PRE1(s-2) -> h1(s-2)
//   Phase B(s): GEMM L1(s-1) ||  EPI-L0 on PRE0(s)  -> h0(s)
// No global ops inside the loop (output staged in LDS OUT, flushed after).
// Projection: M-row 204 (tile 12) carries W_lin over the h1 K-range.

__global__ __launch_bounds__(NTH)
void lstm2_mfma(const float* __restrict__ x,
                const float* __restrict__ W_ih0, const float* __restrict__ W_hh0,
                const float* __restrict__ b_ih0, const float* __restrict__ b_hh0,
                const float* __restrict__ W_ih1, const float* __restrict__ W_hh1,
                const float* __restrict__ b_ih1, const float* __restrict__ b_hh1,
                const float* __restrict__ W_lin, const float* __restrict__ b_lin,
                float* __restrict__ out)
{
    const int tid = threadIdx.x;
    const int w = tid >> 6;          // wave 0..6; tiles {w, w+7}
    const int l = tid & 63;
    const int n = l & 15;            // column slot (0-3 real batch)
    const int p = l >> 4;            // lane group 0..3

    __shared__ _Float16 H0[2][1024];
    __shared__ _Float16 H1[2][1024];
    __shared__ __align__(16) float PRE0[HID*NBATCH*4];    // 204 x f32x4
    __shared__ __align__(16) float PRE1[HID*NBATCH*4];    // 204 x f32x4
    __shared__ float XS[NBATCH][1032];                    // staged x, padded rows
    __shared__ float OUT[NBATCH][TLEN];                   // staged outputs

    for (int i = tid; i < 1024; i += NTH){
        H0[0][i] = (_Float16)0.f; H0[1][i] = (_Float16)0.f;
        H1[0][i] = (_Float16)0.f; H1[1][i] = (_Float16)0.f;
    }
    const long long bb = (long long)blockIdx.x * NBATCH;
    for (int i = tid; i < NBATCH*TLEN; i += NTH){
        const int r = i >> 10, c = i & 1023;
        XS[r][c] = x[(bb + r)*TLEN + c];
    }

    // ---- GEMM-role: persistent fp16 weight fragments + C-init consts ----
    f16x8 A0[2][2];   // W_hh0, K=64
    f16x8 A1[2][4];   // [0..1]=W_ih1 (k<64), [2..3]=W_hh1 (k64..127) + proj row 204
    f32x4 b0c[2], wx0c[2], b1c[2];
    int  jet[2]; bool stAt[2];
    #pragma unroll
    for (int t=0; t<2; ++t){
        const int tile = w + 7*t;             // 0..13 (13 = zero dummy)
        const int ar = 16*tile + n;           // A-row = gate g = 4j + r
        const int aj = ar >> 2, arr = ar & 3;
        const bool rowv = (aj < HID);
        const int orow = arr*HID + aj;
        const float gsc = (arr == 2) ? 2.f*LOG2E : LOG2E;
        #pragma unroll
        for (int kb=0; kb<2; ++kb){
            f16x8 hi;
            #pragma unroll
            for (int jj=0; jj<8; ++jj){
                const int k = kb*32 + 8*p + jj;
                const float wv = (rowv && k < HID) ? gsc * W_hh0[orow*HID + k] : 0.f;
                hi[jj] = (_Float16)wv;
            }
            A0[t][kb] = hi;
        }
        #pragma unroll
        for (int kb=0; kb<4; ++kb){
            f16x8 hi;
            #pragma unroll
            for (int jj=0; jj<8; ++jj){
                const int k = kb*32 + 8*p + jj;   // 0..127: [h0 ; h1]
                float wv = 0.f;
                if (rowv){
                    if (k < 64) { if (k < HID) wv = gsc * W_ih1[orow*HID + k]; }
                    else        { const int kk = k - 64; if (kk < HID) wv = gsc * W_hh1[orow*HID + kk]; }
                } else if (ar == 204 && k >= 64){ // projection row (unscaled!)
                    const int kk = k - 64; if (kk < HID) wv = W_lin[kk];
                }
                hi[jj] = (_Float16)wv;
            }
            A1[t][kb] = hi;
        }
        jet[t]  = 4*tile + p;
        stAt[t] = (n < NBATCH) && (jet[t] < HID);
        const bool jev = (jet[t] < HID) && (tile < 13);
        #pragma unroll
        for (int r4=0; r4<4; ++r4){
            const float gs4 = (r4 == 2) ? 2.f*LOG2E : LOG2E;
            const int oe = r4*HID + jet[t];
            b0c[t][r4]  = jev ? gs4 * (b_ih0[oe] + b_hh0[oe]) : 0.f;
            wx0c[t][r4] = jev ? gs4 * W_ih0[oe] : 0.f;
            b1c[t][r4]  = jev ? gs4 * (b_ih1[oe] + b_hh1[oe]) : 0.f;
        }
    }
    const bool outm = (w == 5) && (p == 3) && (n < NBATCH);   // tile 12, row 204
    const float blin = b_lin[0];

    // ---- epilogue-role: one pure-gate chain per lane (concentrated ranges) ----
    const int q = tid;
    const bool eact = (q < 2*HID*NBATCH);     // 408 chains
    const int lay = (q >= HID*NBATCH) ? 1 : 0;  // 0: phase B, 1: phase A
    const int qq = q - lay*HID*NBATCH;
    const int jq = qq >> 2, nq = qq & 3;
    const int widxq = ((jq>>5)<<9) + (nq + ((jq>>3)&3)*16)*8 + (jq&7);
    float cst = 0.f;    // cell state of this lane's (layer, unit, batch)

    __syncthreads();

    for (int s = 0; s <= TLEN + 1; ++s){
        const int pw = s & 1, prv = pw ^ 1;

        // ================= PHASE A =================
        // rb = h0(s-1) fragments — used by L0 now AND L1 in phase B (reg-carried)
        f16x8 rb[2];
        #pragma unroll
        for (int kb=0; kb<2; ++kb)
            rb[kb] = *reinterpret_cast<const f16x8*>(&H0[prv][kb*512 + l*8]);

        if (s < TLEN){
            const float xv = XS[n & 3][s];
            f32x4 a0 = b0c[0], a1 = b0c[1];
            #pragma unroll
            for (int r4=0; r4<4; ++r4){
                a0[r4] = fmaf(xv, wx0c[0][r4], a0[r4]);
                a1[r4] = fmaf(xv, wx0c[1][r4], a1[r4]);
            }
            __builtin_amdgcn_s_setprio(1);
            a0 = __builtin_amdgcn_mfma_f32_16x16x32_f16(A0[0][0], rb[0], a0, 0,0,0);
            a1 = __builtin_amdgcn_mfma_f32_16x16x32_f16(A0[1][0], rb[0], a1, 0,0,0);
            a0 = __builtin_amdgcn_mfma_f32_16x16x32_f16(A0[0][1], rb[1], a0, 0,0,0);
            a1 = __builtin_amdgcn_mfma_f32_16x16x32_f16(A0[1][1], rb[1], a1, 0,0,0);
            __builtin_amdgcn_s_setprio(0);
            if (stAt[0]) *reinterpret_cast<f32x4*>(&PRE0[(jet[0]*NBATCH + n)*4]) = a0;
            if (stAt[1]) *reinterpret_cast<f32x4*>(&PRE0[(jet[1]*NBATCH + n)*4]) = a1;
        }
        // EPI-L1: gates of L1(s-2) from PRE1 -> h1(s-2) into H1[s&1]
        if (eact && lay == 1 && s >= 2 && s <= TLEN + 1){
            const f32x4 pre = *reinterpret_cast<const f32x4*>(&PRE1[qq*4]);
            const float gi = sigm2(pre[0]);
            const float gf = sigm2(pre[1]);
            const float gg = fmaf(2.f, sigm2(pre[2]), -1.f);
            const float go = sigm2(pre[3]);
            cst = fmaf(gf, cst, gi*gg);
            H1[pw][widxq] = (_Float16)(go * tanh_c(cst));
        }
        __syncthreads();   // #1: PRE0(s), h1(s-2) visible

        // ================= PHASE B =================
        if (s >= 1){
            // r1 = h1(s-2) fragments (just published)
            f16x8 r1[2];
            #pragma unroll
            for (int kb=0; kb<2; ++kb)
                r1[kb] = *reinterpret_cast<const f16x8*>(&H1[pw][kb*512 + l*8]);
            __builtin_amdgcn_s_setprio(1);
            f32x4 b0 = b1c[0], b1 = {0.f,0.f,0.f,0.f};
            f32x4 c0 = b1c[1], c1 = {0.f,0.f,0.f,0.f};
            b0 = __builtin_amdgcn_mfma_f32_16x16x32_f16(A1[0][0], rb[0], b0, 0,0,0);
            c0 = __builtin_amdgcn_mfma_f32_16x16x32_f16(A1[1][0], rb[0], c0, 0,0,0);
            b1 = __builtin_amdgcn_mfma_f32_16x16x32_f16(A1[0][2], r1[0], b1, 0,0,0);
            c1 = __builtin_amdgcn_mfma_f32_16x16x32_f16(A1[1][2], r1[0], c1, 0,0,0);
            b0 = __builtin_amdgcn_mfma_f32_16x16x32_f16(A1[0][1], rb[1], b0, 0,0,0);
            c0 = __builtin_amdgcn_mfma_f32_16x16x32_f16(A1[1][1], rb[1], c0, 0,0,0);
            b1 = __builtin_amdgcn_mfma_f32_16x16x32_f16(A1[0][3], r1[1], b1, 0,0,0);
            c1 = __builtin_amdgcn_mfma_f32_16x16x32_f16(A1[1][3], r1[1], c1, 0,0,0);
            __builtin_amdgcn_s_setprio(0);
            const f32x4 preT0 = b0 + b1;
            const f32x4 preT1 = c0 + c1;
            if (s <= TLEN){
                if (stAt[0]) *reinterpret_cast<f32x4*>(&PRE1[(jet[0]*NBATCH + n)*4]) = preT0;
                if (stAt[1]) *reinterpret_cast<f32x4*>(&PRE1[(jet[1]*NBATCH + n)*4]) = preT1;
            }
            if (outm && s >= 2)
                OUT[n][s-2] = preT1[0] + blin;   // LDS-staged output
        }
        // EPI-L0: gates of L0(s) from PRE0 -> h0(s) into H0[s&1]
        if (eact && lay == 0 && s < TLEN){
            const f32x4 pre = *reinterpret_cast<const f32x4*>(&PRE0[qq*4]);
            const float gi = sigm2(pre[0]);
            const float gf = sigm2(pre[1]);
            const float gg = fmaf(2.f, sigm2(pre[2]), -1.f);
            const float go = sigm2(pre[3]);
            cst = fmaf(gf, cst, gi*gg);
            H0[pw][widxq] = (_Float16)(go * tanh_c(cst));
        }
        __syncthreads();   // #2: PRE1(s-1), h0(s) visible
    }

    // cooperative coalesced flush of staged outputs
    for (int i = tid; i < NBATCH*TLEN; i += NTH){
        const int r = i >> 10, c = i & 1023;
        out[(bb + r)*TLEN + c] = OUT[r][c];
    }
}

extern "C" void kernel_launch(void* const* d_in, const int* in_sizes, int n_in,
                              void* d_out, int out_size, void* d_ws, size_t ws_size,
                              hipStream_t stream) {
    const float* x     = (const float*)d_in[0];
    const float* W_ih0 = (const float*)d_in[1];
    const float* W_hh0 = (const float*)d_in[2];
    const float* b_ih0 = (const float*)d_in[3];
    const float* b_hh0 = (const float*)d_in[4];
    const float* W_ih1 = (const float*)d_in[5];
    const float* W_hh1 = (const float*)d_in[6];
    const float* b_ih1 = (const float*)d_in[7];
    const float* b_hh1 = (const float*)d_in[8];
    const float* W_lin = (const float*)d_in[9];
    const float* b_lin = (const float*)d_in[10];
    float* out = (float*)d_out;

    const int B = in_sizes[0] / TLEN;
    lstm2_mfma<<<dim3(B / NBATCH), dim3(NTH), 0, stream>>>(
        x, W_ih0, W_hh0, b_ih0, b_hh0, W_ih1, W_hh1, b_ih1, b_hh1, W_lin, b_lin, out);
}